// Round 1
// baseline (42058.612 us; speedup 1.0000x reference)
//
#include <hip/hip_runtime.h>
#include <cstddef>

// ---------------------------------------------------------------------------
// RNN_Reverser: 2-layer Elman encoder (1023 steps) -> 2-cell decoder with
// teacher forcing (1023 steps) -> linear head -> log_softmax.
// Round 1: correctness-first fp32 scalar design.
//   - batch (256) split across 128 blocks x 2 rows; recurrence is independent
//     per batch row, so no inter-block sync is ever needed (enc final state ==
//     dec initial state within the same block).
//   - prep kernel packs all weights transposed into ws as [k/4][col][4] float4
//     so per-lane weight loads are coalesced 16B; K padded to multiple of 4.
//   - h state in LDS, read as broadcast float4; combined biases precomputed.
// ---------------------------------------------------------------------------

namespace {
constexpr int TSTEPS = 1023;   // SEQ-1
constexpr int BATCH  = 256;
constexpr int IND    = 131;
constexpr int OUTD   = 131;

// ws layout (float offsets). Packed weight segment sizes: chunks*cols*4.
constexpr int OFF_EW0 = 0;        // enc_Wih0: 33 chunks x 256 = 33792
constexpr int OFF_EH0 = 33792;    // enc_Whh0: 64 x 256 x 4 = 65536
constexpr int OFF_EW1 = 99328;    // enc_Wih1: 65536
constexpr int OFF_EH1 = 164864;   // enc_Whh1: 65536
constexpr int OFF_DW0 = 230400;   // dec_Wih0: 33792
constexpr int OFF_DH0 = 264192;   // dec_Whh0: 65536
constexpr int OFF_DW1 = 329728;   // dec_Wih1: 65536
constexpr int OFF_DH1 = 395264;   // dec_Whh1: 65536
constexpr int OFF_LW  = 460800;   // lin_W:   64 x 131 x 4 = 33536
constexpr int OFF_EB0 = 494336;   // enc bias0 (bih+bhh): 256
constexpr int OFF_EB1 = 494592;
constexpr int OFF_DB0 = 494848;
constexpr int OFF_DB1 = 495104;
constexpr int WS_TOTAL = 495360;  // ~1.98 MB of floats
}  // namespace

// Pack src[ncols][K] row-major into dst[k4][j][4] (zero-pad k >= K).
__device__ __forceinline__ void packW(float* __restrict__ ws,
                                      const float* __restrict__ src,
                                      int e, int off, int K, int ncols) {
  const int le = e - off;
  const int m = le & 3;
  const int tt = le >> 2;
  const int j = tt % ncols;
  const int k4 = tt / ncols;
  const int k = k4 * 4 + m;
  ws[e] = (k < K) ? src[j * K + k] : 0.f;
}

__global__ void prep_kernel(
    const float* __restrict__ eW0, const float* __restrict__ eH0,
    const float* __restrict__ eb_ih0, const float* __restrict__ eb_hh0,
    const float* __restrict__ eW1, const float* __restrict__ eH1,
    const float* __restrict__ eb_ih1, const float* __restrict__ eb_hh1,
    const float* __restrict__ dW0, const float* __restrict__ dH0,
    const float* __restrict__ db_ih0, const float* __restrict__ db_hh0,
    const float* __restrict__ dW1, const float* __restrict__ dH1,
    const float* __restrict__ db_ih1, const float* __restrict__ db_hh1,
    const float* __restrict__ linW, float* __restrict__ ws) {
  const int e = blockIdx.x * 256 + threadIdx.x;
  if (e >= WS_TOTAL) return;
  if (e < OFF_EH0)      packW(ws, eW0, e, OFF_EW0, IND, 256);
  else if (e < OFF_EW1) packW(ws, eH0, e, OFF_EH0, 256, 256);
  else if (e < OFF_EH1) packW(ws, eW1, e, OFF_EW1, 256, 256);
  else if (e < OFF_DW0) packW(ws, eH1, e, OFF_EH1, 256, 256);
  else if (e < OFF_DH0) packW(ws, dW0, e, OFF_DW0, IND, 256);
  else if (e < OFF_DW1) packW(ws, dH0, e, OFF_DH0, 256, 256);
  else if (e < OFF_DH1) packW(ws, dW1, e, OFF_DW1, 256, 256);
  else if (e < OFF_LW)  packW(ws, dH1, e, OFF_DH1, 256, 256);
  else if (e < OFF_EB0) packW(ws, linW, e, OFF_LW, 256, OUTD);
  else if (e < OFF_EB1) { int j = e - OFF_EB0; ws[e] = eb_ih0[j] + eb_hh0[j]; }
  else if (e < OFF_DB0) { int j = e - OFF_EB1; ws[e] = eb_ih1[j] + eb_hh1[j]; }
  else if (e < OFF_DB1) { int j = e - OFF_DB0; ws[e] = db_ih0[j] + db_hh0[j]; }
  else                  { int j = e - OFF_DB1; ws[e] = db_ih1[j] + db_hh1[j]; }
}

__device__ __forceinline__ float dot4(const float4 a, const float4 b, float acc) {
  acc = fmaf(a.x, b.x, acc);
  acc = fmaf(a.y, b.y, acc);
  acc = fmaf(a.z, b.z, acc);
  acc = fmaf(a.w, b.w, acc);
  return acc;
}

__device__ __forceinline__ float ftanh(float x) {
  // tanh(x) = sign(x) * (1 - e^{-2|x|}) / (1 + e^{-2|x|}); stable for all x.
  const float ax = fabsf(x);
  const float e = __expf(-2.f * ax);
  const float t = __fdividef(1.f - e, 1.f + e);
  return copysignf(t, x);
}

// Layer with external input (K padded 131->132, 33 chunks) + recurrent (64 chunks).
__device__ __forceinline__ float2 layer_in(
    const float4* __restrict__ wih, const float4* __restrict__ whh,
    const float* __restrict__ x0, const float* __restrict__ x1,
    const float* __restrict__ h0, const float* __restrict__ h1,
    const float bias, const int tid) {
  float a0 = bias, a1 = bias;
#pragma unroll 4
  for (int k4 = 0; k4 < 33; ++k4) {
    const float4 w = wih[k4 * 256 + tid];
    a0 = dot4(*(const float4*)(x0 + k4 * 4), w, a0);
    a1 = dot4(*(const float4*)(x1 + k4 * 4), w, a1);
  }
#pragma unroll 4
  for (int k4 = 0; k4 < 64; ++k4) {
    const float4 w = whh[k4 * 256 + tid];
    a0 = dot4(*(const float4*)(h0 + k4 * 4), w, a0);
    a1 = dot4(*(const float4*)(h1 + k4 * 4), w, a1);
  }
  return make_float2(a0, a1);
}

// Layer with hidden-sized input (64 chunks) + recurrent (64 chunks).
__device__ __forceinline__ float2 layer_hh(
    const float4* __restrict__ wih, const float4* __restrict__ whh,
    const float* __restrict__ x0, const float* __restrict__ x1,
    const float* __restrict__ h0, const float* __restrict__ h1,
    const float bias, const int tid) {
  float a0 = bias, a1 = bias;
#pragma unroll 4
  for (int k4 = 0; k4 < 64; ++k4) {
    const float4 wi = wih[k4 * 256 + tid];
    const float4 wh = whh[k4 * 256 + tid];
    a0 = dot4(*(const float4*)(x0 + k4 * 4), wi, a0);
    a1 = dot4(*(const float4*)(x1 + k4 * 4), wi, a1);
    a0 = dot4(*(const float4*)(h0 + k4 * 4), wh, a0);
    a1 = dot4(*(const float4*)(h1 + k4 * 4), wh, a1);
  }
  return make_float2(a0, a1);
}

__global__ __launch_bounds__(256, 1) void rnn_kernel(
    const float* __restrict__ X, const float* __restrict__ Y,
    const float* __restrict__ ws, const float* __restrict__ linb,
    float* __restrict__ out) {
  __shared__ __align__(16) float xb[2][132];
  __shared__ __align__(16) float h0s[2][256];
  __shared__ __align__(16) float h1s[2][256];
  __shared__ __align__(16) float lo[2][132];

  const int tid = threadIdx.x;
  const int r0 = blockIdx.x * 2;  // this block's 2 batch rows

  const float4* ew0 = (const float4*)(ws + OFF_EW0);
  const float4* eh0 = (const float4*)(ws + OFF_EH0);
  const float4* ew1 = (const float4*)(ws + OFF_EW1);
  const float4* eh1 = (const float4*)(ws + OFF_EH1);
  const float4* dw0 = (const float4*)(ws + OFF_DW0);
  const float4* dh0 = (const float4*)(ws + OFF_DH0);
  const float4* dw1 = (const float4*)(ws + OFF_DW1);
  const float4* dh1 = (const float4*)(ws + OFF_DH1);
  const float4* lw  = (const float4*)(ws + OFF_LW);
  const float eb0v = ws[OFF_EB0 + tid];
  const float eb1v = ws[OFF_EB1 + tid];
  const float db0v = ws[OFF_DB0 + tid];
  const float db1v = ws[OFF_DB1 + tid];

  h0s[0][tid] = 0.f; h0s[1][tid] = 0.f;
  h1s[0][tid] = 0.f; h1s[1][tid] = 0.f;
  __syncthreads();

  // ------------------------------ encoder ------------------------------
  for (int t = 0; t < TSTEPS; ++t) {
    {
      const int r = tid / 132, i = tid - r * 132;  // covers [0,256)
      xb[r][i] = (i < IND) ? X[((size_t)t * BATCH + r0 + r) * IND + i] : 0.f;
      if (tid < 8) {  // remaining elems of row 1: i in [124,132)
        const int i2 = tid + 124;
        xb[1][i2] = (i2 < IND) ? X[((size_t)t * BATCH + r0 + 1) * IND + i2] : 0.f;
      }
    }
    __syncthreads();
    const float2 a = layer_in(ew0, eh0, xb[0], xb[1], h0s[0], h0s[1], eb0v, tid);
    const float n0a = ftanh(a.x), n0b = ftanh(a.y);
    __syncthreads();
    h0s[0][tid] = n0a; h0s[1][tid] = n0b;
    __syncthreads();
    const float2 b = layer_hh(ew1, eh1, h0s[0], h0s[1], h1s[0], h1s[1], eb1v, tid);
    const float n1a = ftanh(b.x), n1b = ftanh(b.y);
    __syncthreads();
    h1s[0][tid] = n1a; h1s[1][tid] = n1b;
    __syncthreads();
  }

  // ------------------------------ decoder ------------------------------
  // Teacher forcing inputs: t==0 -> X[SEQ-1], else Y[t-1].
  for (int t = 0; t < TSTEPS; ++t) {
    const float* xbase = (t == 0) ? (X + (size_t)TSTEPS * BATCH * IND)
                                  : (Y + (size_t)(t - 1) * BATCH * IND);
    {
      const int r = tid / 132, i = tid - r * 132;
      xb[r][i] = (i < IND) ? xbase[(size_t)(r0 + r) * IND + i] : 0.f;
      if (tid < 8) {
        const int i2 = tid + 124;
        xb[1][i2] = (i2 < IND) ? xbase[(size_t)(r0 + 1) * IND + i2] : 0.f;
      }
    }
    __syncthreads();
    const float2 a = layer_in(dw0, dh0, xb[0], xb[1], h0s[0], h0s[1], db0v, tid);
    const float n0a = ftanh(a.x), n0b = ftanh(a.y);
    __syncthreads();
    h0s[0][tid] = n0a; h0s[1][tid] = n0b;
    __syncthreads();
    const float2 b = layer_hh(dw1, dh1, h0s[0], h0s[1], h1s[0], h1s[1], db1v, tid);
    const float n1a = ftanh(b.x), n1b = ftanh(b.y);
    __syncthreads();
    h1s[0][tid] = n1a; h1s[1][tid] = n1b;
    __syncthreads();

    // logits: [2 rows][131]
    if (tid < OUTD) {
      float c0 = linb[tid], c1 = linb[tid];
#pragma unroll 4
      for (int k4 = 0; k4 < 64; ++k4) {
        const float4 w = lw[k4 * OUTD + tid];
        c0 = dot4(*(const float4*)&h1s[0][k4 * 4], w, c0);
        c1 = dot4(*(const float4*)&h1s[1][k4 * 4], w, c1);
      }
      lo[0][tid] = c0;
      lo[1][tid] = c1;
    }
    __syncthreads();

    // log_softmax over 131 classes; wave 0 -> row 0, wave 1 -> row 1.
    const int wid = tid >> 6, lane = tid & 63;
    if (wid < 2) {
      float m = -3.0e38f;
      for (int o = lane; o < OUTD; o += 64) m = fmaxf(m, lo[wid][o]);
#pragma unroll
      for (int off = 32; off > 0; off >>= 1) m = fmaxf(m, __shfl_xor(m, off, 64));
      float s = 0.f;
      for (int o = lane; o < OUTD; o += 64) s += __expf(lo[wid][o] - m);
#pragma unroll
      for (int off = 32; off > 0; off >>= 1) s += __shfl_xor(s, off, 64);
      const float lse = m + __logf(s);
      float* op = out + ((size_t)t * BATCH + r0 + wid) * OUTD;
      for (int o = lane; o < OUTD; o += 64) op[o] = lo[wid][o] - lse;
    }
    __syncthreads();
  }
}

extern "C" void kernel_launch(void* const* d_in, const int* in_sizes, int n_in,
                              void* d_out, int out_size, void* d_ws, size_t ws_size,
                              hipStream_t stream) {
  const float* X       = (const float*)d_in[0];
  const float* Y       = (const float*)d_in[1];
  const float* eW0     = (const float*)d_in[2];
  const float* eH0     = (const float*)d_in[3];
  const float* eb_ih0  = (const float*)d_in[4];
  const float* eb_hh0  = (const float*)d_in[5];
  const float* eW1     = (const float*)d_in[6];
  const float* eH1     = (const float*)d_in[7];
  const float* eb_ih1  = (const float*)d_in[8];
  const float* eb_hh1  = (const float*)d_in[9];
  const float* dW0     = (const float*)d_in[10];
  const float* dH0     = (const float*)d_in[11];
  const float* db_ih0  = (const float*)d_in[12];
  const float* db_hh0  = (const float*)d_in[13];
  const float* dW1     = (const float*)d_in[14];
  const float* dH1     = (const float*)d_in[15];
  const float* db_ih1  = (const float*)d_in[16];
  const float* db_hh1  = (const float*)d_in[17];
  const float* linW    = (const float*)d_in[18];
  const float* linb    = (const float*)d_in[19];
  float* ws  = (float*)d_ws;
  float* out = (float*)d_out;

  prep_kernel<<<(WS_TOTAL + 255) / 256, 256, 0, stream>>>(
      eW0, eH0, eb_ih0, eb_hh0, eW1, eH1, eb_ih1, eb_hh1,
      dW0, dH0, db_ih0, db_hh0, dW1, dH1, db_ih1, db_hh1, linW, ws);
  rnn_kernel<<<128, 256, 0, stream>>>(X, Y, ws, linb, out);
}

// Round 2
// 10005.734 us; speedup vs baseline: 4.2035x; 4.2035x over previous
//
#include <hip/hip_runtime.h>
#include <cstddef>

// ---------------------------------------------------------------------------
// RNN_Reverser round 2: layer-decoupled MFMA design.
//   P = X @ Wih^T + b  (batched over all 1023 steps, full-chip split-bf16 MFMA)
//   scan: h_t = tanh(P_t + h_{t-1} @ Whh^T)  (Whh register-resident per wave)
// Sequence: GEMM1->scan1->GEMM2->scan2->GEMM3(dec in)->scan3->GEMM4->scan4->head.
// All matmuls use split-bf16 (x = hi + lo, C = Ah*Bh + Ah*Bl + Al*Bh) for
// fp32-like precision (missing term ~2^-18 rel) on the bf16 MFMA pipe.
// Scans: 16 blocks x 16 batch rows x 8 waves; A (h state) double-buffered in
// LDS; P read/written in place; 1 barrier per step.
// Fallback to round-1 fp32 kernels if ws_size < ~514 MB.
// ---------------------------------------------------------------------------

typedef __attribute__((ext_vector_type(8))) short short8;
typedef __attribute__((ext_vector_type(4))) float f32x4;

namespace {
constexpr int TSTEPS = 1023;
constexpr int BATCH = 256;
constexpr int IND = 131;
constexpr int OUTD = 131;
constexpr int MTOT = TSTEPS * BATCH;  // 261888

// fast path ws layout (bytes)
constexpr size_t SB = (size_t)MTOT * 256 * 4;  // 268,173,312 one P/out buffer
// pack region: ushort offsets
constexpr int UE0 = 0;        // each U pack: hi 65536 + lo 65536
constexpr int UE1 = 131072;
constexpr int UD0 = 262144;
constexpr int UD1 = 393216;
constexpr int EW0 = 524288;   // proj K=131: hi 40960 + lo 40960
constexpr int DW0 = 606208;
constexpr int EW1 = 688128;   // proj K=256: hi 65536 + lo 65536
constexpr int DW1 = 819200;
constexpr int LINP = 950272;  // lin: hi 36864 + lo 36864
constexpr int PK_USH = 1024000;
constexpr size_t PKB = 2 * SB;                   // pack base (bytes)
constexpr size_t BFB = PKB + 2 * (size_t)PK_USH; // bias/finals float region
// float offsets inside BFB region: be0 0, be1 256, bd0 512, bd1 768, blin 1024(144)
constexpr int FIN0 = 1168;
constexpr int FIN1 = 1168 + 65536;
constexpr size_t TOTAL_WS = BFB + (size_t)(1168 + 2 * 65536) * 4;  // 538,923,584

// slow path (round 1) float offsets
constexpr int OFF_EW0s = 0, OFF_EH0s = 33792, OFF_EW1s = 99328, OFF_EH1s = 164864;
constexpr int OFF_DW0s = 230400, OFF_DH0s = 264192, OFF_DW1s = 329728, OFF_DH1s = 395264;
constexpr int OFF_LWs = 460800, OFF_EB0s = 494336, OFF_EB1s = 494592;
constexpr int OFF_DB0s = 494848, OFF_DB1s = 495104;
constexpr int WS_TOTAL_SLOW = 495360;
}  // namespace

__device__ __forceinline__ unsigned short f2bf(float x) {
  unsigned u = __float_as_uint(x);
  u += 0x7fffu + ((u >> 16) & 1u);
  return (unsigned short)(u >> 16);
}
__device__ __forceinline__ float bf2f(unsigned short h) {
  return __uint_as_float(((unsigned)h) << 16);
}
__device__ __forceinline__ float ftanh(float x) {
  const float ax = fabsf(x);
  const float e = __expf(-2.f * ax);
  const float t = __fdividef(1.f - e, 1.f + e);
  return copysignf(t, x);
}
__device__ __forceinline__ f32x4 mfma16(uint4 a, uint4 b, f32x4 c) {
  return __builtin_amdgcn_mfma_f32_16x16x32_bf16(
      __builtin_bit_cast(short8, a), __builtin_bit_cast(short8, b), c, 0, 0, 0);
}

// ------------------------------- prep (fast) -------------------------------
// Packs all weights as hi/lo bf16 in MFMA B-fragment order:
//   frag element (kk, tile, lane, j) <- W[tile*16 + (lane&15)][kk*32 + (lane>>4)*8 + j]
__global__ void prep_pack(
    const float* __restrict__ eW0, const float* __restrict__ eH0,
    const float* __restrict__ eb_ih0, const float* __restrict__ eb_hh0,
    const float* __restrict__ eW1, const float* __restrict__ eH1,
    const float* __restrict__ eb_ih1, const float* __restrict__ eb_hh1,
    const float* __restrict__ dW0, const float* __restrict__ dH0,
    const float* __restrict__ db_ih0, const float* __restrict__ db_hh0,
    const float* __restrict__ dW1, const float* __restrict__ dH1,
    const float* __restrict__ db_ih1, const float* __restrict__ db_hh1,
    const float* __restrict__ linW, const float* __restrict__ linb,
    unsigned short* __restrict__ pk, float* __restrict__ bfin) {
  const int e = blockIdx.x * 256 + threadIdx.x;
  if (e >= 513168) return;
  if (e < 262144) {  // recurrent U matrices (256x256)
    const int um = e >> 16, le = e & 65535;
    const int j = le & 7, lane = (le >> 3) & 63, tile = (le >> 9) & 15, kk = le >> 13;
    const int n = tile * 16 + (lane & 15), k = kk * 32 + ((lane >> 4) << 3) + j;
    const float* U = (um == 0) ? eH0 : (um == 1) ? eH1 : (um == 2) ? dH0 : dH1;
    const float x = U[n * 256 + k];
    const unsigned short h = f2bf(x);
    const int base = um * 131072;
    pk[base + le] = h;
    pk[base + 65536 + le] = f2bf(x - bf2f(h));
  } else if (e < 344064) {  // eW0 / dW0 (256x131, K pad 160, KK=5)
    const bool isD = (e >= 303104);
    const int e2 = e - (isD ? 303104 : 262144);
    const int j = e2 & 7, lane = (e2 >> 3) & 63, tile = (e2 >> 9) & 15, kk = e2 >> 13;
    const int n = tile * 16 + (lane & 15), k = kk * 32 + ((lane >> 4) << 3) + j;
    const float* W = isD ? dW0 : eW0;
    const float x = (k < IND) ? W[n * IND + k] : 0.f;
    const unsigned short h = f2bf(x);
    const int base = isD ? DW0 : EW0;
    pk[base + e2] = h;
    pk[base + 40960 + e2] = f2bf(x - bf2f(h));
  } else if (e < 475136) {  // eW1 / dW1 (256x256, KK=8)
    const bool isD = (e >= 409600);
    const int e2 = e - (isD ? 409600 : 344064);
    const int j = e2 & 7, lane = (e2 >> 3) & 63, tile = (e2 >> 9) & 15, kk = e2 >> 13;
    const int n = tile * 16 + (lane & 15), k = kk * 32 + ((lane >> 4) << 3) + j;
    const float* W = isD ? dW1 : eW1;
    const float x = W[n * 256 + k];
    const unsigned short h = f2bf(x);
    const int base = isD ? DW1 : EW1;
    pk[base + e2] = h;
    pk[base + 65536 + e2] = f2bf(x - bf2f(h));
  } else if (e < 512000) {  // lin_W (131x256 -> 144 cols pad, 9 tiles, KK=8)
    const int e2 = e - 475136;
    const int kk = e2 / 4608;
    const int rem = e2 - kk * 4608;
    const int t9 = rem >> 9, le = rem & 511;
    const int j = le & 7, lane = le >> 3;
    const int n = t9 * 16 + (lane & 15), k = kk * 32 + ((lane >> 4) << 3) + j;
    const float x = (n < OUTD) ? linW[n * 256 + k] : 0.f;
    const unsigned short h = f2bf(x);
    pk[LINP + e2] = h;
    pk[LINP + 36864 + e2] = f2bf(x - bf2f(h));
  } else {  // combined biases + padded lin bias
    const int e3 = e - 512000;
    if (e3 < 256) bfin[e3] = eb_ih0[e3] + eb_hh0[e3];
    else if (e3 < 512) { const int j = e3 - 256; bfin[e3] = eb_ih1[j] + eb_hh1[j]; }
    else if (e3 < 768) { const int j = e3 - 512; bfin[e3] = db_ih0[j] + db_hh0[j]; }
    else if (e3 < 1024){ const int j = e3 - 768; bfin[e3] = db_ih1[j] + db_hh1[j]; }
    else { const int j = e3 - 1024; bfin[e3] = (j < OUTD) ? linb[j] : -1e30f; }
  }
}

// ------------------------- batched input projection ------------------------
// P[m][0..255] = A[m][0..K) @ W^T + bias ; grid (MTOT/64, 4), block 256.
__global__ __launch_bounds__(256) void gemm_proj(
    const float* __restrict__ A, const float* __restrict__ X1023,
    const float* __restrict__ Yp, const int amode, const int K, const int KK,
    const unsigned short* __restrict__ Wh, const unsigned short* __restrict__ Wl,
    const float* __restrict__ bias, float* __restrict__ Pout) {
  __shared__ unsigned short Ah[64][40];
  __shared__ unsigned short Al[64][40];
  const int tid = threadIdx.x, lane = tid & 63, wid = tid >> 6;
  const int mbase = blockIdx.x * 64;
  const int cg = blockIdx.y;
  const int srow = tid >> 2, kidx = (tid & 3) << 3;
  const float* rowptr;
  {
    const int grow = mbase + srow;
    if (amode) {
      const int t = grow >> 8, b = grow & 255;
      rowptr = t ? (Yp + ((size_t)(t - 1) * 256 + b) * IND) : (X1023 + (size_t)b * IND);
    } else {
      rowptr = A + (size_t)grow * K;
    }
  }
  const f32x4 z = {0.f, 0.f, 0.f, 0.f};
  f32x4 acc[4] = {z, z, z, z};
  const uint4* Wh4 = (const uint4*)Wh;
  const uint4* Wl4 = (const uint4*)Wl;
  for (int kk = 0; kk < KK; ++kk) {
    const int k0 = kk << 5;
    __syncthreads();
    float v[8];
#pragma unroll
    for (int j = 0; j < 8; ++j) {
      const int kg = k0 + kidx + j;
      v[j] = (kg < K) ? rowptr[kg] : 0.f;
    }
#pragma unroll
    for (int j = 0; j < 8; ++j) {
      const unsigned short h = f2bf(v[j]);
      Ah[srow][kidx + j] = h;
      Al[srow][kidx + j] = f2bf(v[j] - bf2f(h));
    }
    __syncthreads();
    const uint4 avh = *(const uint4*)&Ah[(wid << 4) + (lane & 15)][(lane >> 4) << 3];
    const uint4 avl = *(const uint4*)&Al[(wid << 4) + (lane & 15)][(lane >> 4) << 3];
#pragma unroll
    for (int tt = 0; tt < 4; ++tt) {
      const int bi = ((kk << 4) + (cg << 2) + tt) * 64 + lane;
      const uint4 bh = Wh4[bi], bl = Wl4[bi];
      acc[tt] = mfma16(avh, bh, acc[tt]);
      acc[tt] = mfma16(avh, bl, acc[tt]);
      acc[tt] = mfma16(avl, bh, acc[tt]);
    }
  }
#pragma unroll
  for (int tt = 0; tt < 4; ++tt) {
    const int col = ((cg << 2) + tt) * 16 + (lane & 15);
    const float bcol = bias[col];
#pragma unroll
    for (int r = 0; r < 4; ++r) {
      const int row = mbase + (wid << 4) + ((lane >> 4) << 2) + r;
      Pout[(size_t)row * 256 + col] = acc[tt][r] + bcol;
    }
  }
}

// ----------------------------------- scan ----------------------------------
// In-place: P_t (precomputed proj+bias) -> out_t = tanh(P_t + h_{t-1} U^T).
// 16 blocks x 16 rows; 8 waves, each owns 2 column tiles with U hi/lo in regs.
__global__ __launch_bounds__(512, 2) void scan_kernel(
    float* __restrict__ P, const unsigned short* __restrict__ Uh,
    const float* __restrict__ hinit, float* __restrict__ finals) {
  __shared__ unsigned short Ah[2][16][264];
  __shared__ unsigned short Al[2][16][264];
  const int tid = threadIdx.x, lane = tid & 63, wid = tid >> 6;
  const int r0 = blockIdx.x << 4;
  const uint4* U4 = (const uint4*)Uh;  // lo component at +8192 uint4
  uint4 uf[2][2][8];                   // [hi/lo][tile][kk]
#pragma unroll
  for (int tt = 0; tt < 2; ++tt)
#pragma unroll
    for (int kk = 0; kk < 8; ++kk) {
      const int idx = ((kk << 4) + wid * 2 + tt) * 64 + lane;
      uf[0][tt][kk] = U4[idx];
      uf[1][tt][kk] = U4[idx + 8192];
    }
#pragma unroll
  for (int j = 0; j < 8; ++j) {  // init h_{-1}
    const int e = tid * 8 + j;
    const int row = e >> 8, col = e & 255;
    const float x = hinit ? hinit[((r0 + row) << 8) + col] : 0.f;
    const unsigned short h = f2bf(x);
    Ah[0][row][col] = h;
    Al[0][row][col] = f2bf(x - bf2f(h));
  }
  __syncthreads();
  const int rowl = (lane >> 4) << 2;
  const int col0 = (wid * 2) * 16 + (lane & 15);
  float* pbase = P + (((size_t)(r0 + rowl)) << 8) + col0;
  float* fbase = finals ? (finals + (((size_t)(r0 + rowl)) << 8) + col0) : (float*)0;
  for (int t = 0; t < TSTEPS; ++t) {
    const int cur = t & 1, nxt = cur ^ 1;
    float* pt = pbase + (size_t)t * 65536;
    float p[2][4];
#pragma unroll
    for (int tt = 0; tt < 2; ++tt)
#pragma unroll
      for (int r = 0; r < 4; ++r) p[tt][r] = pt[tt * 16 + r * 256];
    const f32x4 z = {0.f, 0.f, 0.f, 0.f};
    f32x4 a0 = z, a1 = z;
#pragma unroll
    for (int kk = 0; kk < 8; ++kk) {
      const uint4 avh = *(const uint4*)&Ah[cur][lane & 15][(kk << 5) + ((lane >> 4) << 3)];
      const uint4 avl = *(const uint4*)&Al[cur][lane & 15][(kk << 5) + ((lane >> 4) << 3)];
      a0 = mfma16(avh, uf[0][0][kk], a0);
      a1 = mfma16(avh, uf[0][1][kk], a1);
      a0 = mfma16(avh, uf[1][0][kk], a0);
      a1 = mfma16(avh, uf[1][1][kk], a1);
      a0 = mfma16(avl, uf[0][0][kk], a0);
      a1 = mfma16(avl, uf[0][1][kk], a1);
    }
#pragma unroll
    for (int tt = 0; tt < 2; ++tt) {
#pragma unroll
      for (int r = 0; r < 4; ++r) {
        const float av = tt ? a1[r] : a0[r];
        const float x = ftanh(av + p[tt][r]);
        pt[tt * 16 + r * 256] = x;
        if (fbase && t == TSTEPS - 1) fbase[tt * 16 + r * 256] = x;
        const unsigned short h = f2bf(x);
        Ah[nxt][rowl + r][col0 + tt * 16] = h;
        Al[nxt][rowl + r][col0 + tt * 16] = f2bf(x - bf2f(h));
      }
    }
    __syncthreads();
  }
}

// ------------------------------ head + softmax -----------------------------
__global__ __launch_bounds__(256) void head_kernel(
    const float* __restrict__ A, const unsigned short* __restrict__ Wh,
    const unsigned short* __restrict__ Wl, const float* __restrict__ biasp,
    float* __restrict__ out) {
  __shared__ unsigned short Ah[64][40];
  __shared__ unsigned short Al[64][40];
  const int tid = threadIdx.x, lane = tid & 63, wid = tid >> 6;
  const int mbase = blockIdx.x * 64;
  const int srow = tid >> 2, kidx = (tid & 3) << 3;
  const float* rowptr = A + (size_t)(mbase + srow) * 256;
  const f32x4 z = {0.f, 0.f, 0.f, 0.f};
  f32x4 acc[9] = {z, z, z, z, z, z, z, z, z};
  const uint4* Wh4 = (const uint4*)Wh;
  const uint4* Wl4 = (const uint4*)Wl;
  for (int kk = 0; kk < 8; ++kk) {
    const int k0 = kk << 5;
    __syncthreads();
#pragma unroll
    for (int j = 0; j < 8; ++j) {
      const float v = rowptr[k0 + kidx + j];
      const unsigned short h = f2bf(v);
      Ah[srow][kidx + j] = h;
      Al[srow][kidx + j] = f2bf(v - bf2f(h));
    }
    __syncthreads();
    const uint4 avh = *(const uint4*)&Ah[(wid << 4) + (lane & 15)][(lane >> 4) << 3];
    const uint4 avl = *(const uint4*)&Al[(wid << 4) + (lane & 15)][(lane >> 4) << 3];
#pragma unroll
    for (int tt = 0; tt < 9; ++tt) {
      const int bi = (kk * 9 + tt) * 64 + lane;
      const uint4 bh = Wh4[bi], bl = Wl4[bi];
      acc[tt] = mfma16(avh, bh, acc[tt]);
      acc[tt] = mfma16(avh, bl, acc[tt]);
      acc[tt] = mfma16(avl, bh, acc[tt]);
    }
  }
#pragma unroll
  for (int tt = 0; tt < 9; ++tt) {
    const float b = biasp[tt * 16 + (lane & 15)];
#pragma unroll
    for (int r = 0; r < 4; ++r) acc[tt][r] += b;
  }
  float lse[4];
#pragma unroll
  for (int r = 0; r < 4; ++r) {
    float m = acc[0][r];
#pragma unroll
    for (int tt = 1; tt < 9; ++tt) m = fmaxf(m, acc[tt][r]);
    m = fmaxf(m, __shfl_xor(m, 1));
    m = fmaxf(m, __shfl_xor(m, 2));
    m = fmaxf(m, __shfl_xor(m, 4));
    m = fmaxf(m, __shfl_xor(m, 8));
    float s = 0.f;
#pragma unroll
    for (int tt = 0; tt < 9; ++tt) s += __expf(acc[tt][r] - m);
    s += __shfl_xor(s, 1);
    s += __shfl_xor(s, 2);
    s += __shfl_xor(s, 4);
    s += __shfl_xor(s, 8);
    lse[r] = m + __logf(s);
  }
#pragma unroll
  for (int tt = 0; tt < 9; ++tt) {
    const int col = tt * 16 + (lane & 15);
    if (col < OUTD) {
#pragma unroll
      for (int r = 0; r < 4; ++r) {
        const int row = mbase + (wid << 4) + ((lane >> 4) << 2) + r;
        out[(size_t)row * OUTD + col] = acc[tt][r] - lse[r];
      }
    }
  }
}

// ========================= slow fallback (round 1) =========================
__device__ __forceinline__ void packWs(float* __restrict__ ws, const float* __restrict__ src,
                                       int e, int off, int K, int ncols) {
  const int le = e - off;
  const int m = le & 3;
  const int tt = le >> 2;
  const int j = tt % ncols;
  const int k4 = tt / ncols;
  const int k = k4 * 4 + m;
  ws[e] = (k < K) ? src[j * K + k] : 0.f;
}

__global__ void prep_slow(
    const float* __restrict__ eW0, const float* __restrict__ eH0,
    const float* __restrict__ eb_ih0, const float* __restrict__ eb_hh0,
    const float* __restrict__ eW1, const float* __restrict__ eH1,
    const float* __restrict__ eb_ih1, const float* __restrict__ eb_hh1,
    const float* __restrict__ dW0, const float* __restrict__ dH0,
    const float* __restrict__ db_ih0, const float* __restrict__ db_hh0,
    const float* __restrict__ dW1, const float* __restrict__ dH1,
    const float* __restrict__ db_ih1, const float* __restrict__ db_hh1,
    const float* __restrict__ linW, float* __restrict__ ws) {
  const int e = blockIdx.x * 256 + threadIdx.x;
  if (e >= WS_TOTAL_SLOW) return;
  if (e < OFF_EH0s)      packWs(ws, eW0, e, OFF_EW0s, IND, 256);
  else if (e < OFF_EW1s) packWs(ws, eH0, e, OFF_EH0s, 256, 256);
  else if (e < OFF_EH1s) packWs(ws, eW1, e, OFF_EW1s, 256, 256);
  else if (e < OFF_DW0s) packWs(ws, eH1, e, OFF_EH1s, 256, 256);
  else if (e < OFF_DH0s) packWs(ws, dW0, e, OFF_DW0s, IND, 256);
  else if (e < OFF_DW1s) packWs(ws, dH0, e, OFF_DH0s, 256, 256);
  else if (e < OFF_DH1s) packWs(ws, dW1, e, OFF_DW1s, 256, 256);
  else if (e < OFF_LWs)  packWs(ws, dH1, e, OFF_DH1s, 256, 256);
  else if (e < OFF_EB0s) packWs(ws, linW, e, OFF_LWs, 256, OUTD);
  else if (e < OFF_EB1s) { int j = e - OFF_EB0s; ws[e] = eb_ih0[j] + eb_hh0[j]; }
  else if (e < OFF_DB0s) { int j = e - OFF_EB1s; ws[e] = eb_ih1[j] + eb_hh1[j]; }
  else if (e < OFF_DB1s) { int j = e - OFF_DB0s; ws[e] = db_ih0[j] + db_hh0[j]; }
  else                   { int j = e - OFF_DB1s; ws[e] = db_ih1[j] + db_hh1[j]; }
}

__device__ __forceinline__ float dot4(const float4 a, const float4 b, float acc) {
  acc = fmaf(a.x, b.x, acc);
  acc = fmaf(a.y, b.y, acc);
  acc = fmaf(a.z, b.z, acc);
  acc = fmaf(a.w, b.w, acc);
  return acc;
}

__device__ __forceinline__ float2 layer_in(
    const float4* __restrict__ wih, const float4* __restrict__ whh,
    const float* __restrict__ x0, const float* __restrict__ x1,
    const float* __restrict__ h0, const float* __restrict__ h1,
    const float bias, const int tid) {
  float a0 = bias, a1 = bias;
#pragma unroll 4
  for (int k4 = 0; k4 < 33; ++k4) {
    const float4 w = wih[k4 * 256 + tid];
    a0 = dot4(*(const float4*)(x0 + k4 * 4), w, a0);
    a1 = dot4(*(const float4*)(x1 + k4 * 4), w, a1);
  }
#pragma unroll 4
  for (int k4 = 0; k4 < 64; ++k4) {
    const float4 w = whh[k4 * 256 + tid];
    a0 = dot4(*(const float4*)(h0 + k4 * 4), w, a0);
    a1 = dot4(*(const float4*)(h1 + k4 * 4), w, a1);
  }
  return make_float2(a0, a1);
}

__device__ __forceinline__ float2 layer_hh(
    const float4* __restrict__ wih, const float4* __restrict__ whh,
    const float* __restrict__ x0, const float* __restrict__ x1,
    const float* __restrict__ h0, const float* __restrict__ h1,
    const float bias, const int tid) {
  float a0 = bias, a1 = bias;
#pragma unroll 4
  for (int k4 = 0; k4 < 64; ++k4) {
    const float4 wi = wih[k4 * 256 + tid];
    const float4 wh = whh[k4 * 256 + tid];
    a0 = dot4(*(const float4*)(x0 + k4 * 4), wi, a0);
    a1 = dot4(*(const float4*)(x1 + k4 * 4), wi, a1);
    a0 = dot4(*(const float4*)(h0 + k4 * 4), wh, a0);
    a1 = dot4(*(const float4*)(h1 + k4 * 4), wh, a1);
  }
  return make_float2(a0, a1);
}

__global__ __launch_bounds__(256, 1) void rnn_slow(
    const float* __restrict__ X, const float* __restrict__ Y,
    const float* __restrict__ ws, const float* __restrict__ linb,
    float* __restrict__ out) {
  __shared__ __align__(16) float xb[2][132];
  __shared__ __align__(16) float h0s[2][256];
  __shared__ __align__(16) float h1s[2][256];
  __shared__ __align__(16) float lo[2][132];
  const int tid = threadIdx.x;
  const int r0 = blockIdx.x * 2;
  const float4* ew0 = (const float4*)(ws + OFF_EW0s);
  const float4* eh0 = (const float4*)(ws + OFF_EH0s);
  const float4* ew1 = (const float4*)(ws + OFF_EW1s);
  const float4* eh1 = (const float4*)(ws + OFF_EH1s);
  const float4* dw0 = (const float4*)(ws + OFF_DW0s);
  const float4* dh0 = (const float4*)(ws + OFF_DH0s);
  const float4* dw1 = (const float4*)(ws + OFF_DW1s);
  const float4* dh1 = (const float4*)(ws + OFF_DH1s);
  const float4* lw  = (const float4*)(ws + OFF_LWs);
  const float eb0v = ws[OFF_EB0s + tid];
  const float eb1v = ws[OFF_EB1s + tid];
  const float db0v = ws[OFF_DB0s + tid];
  const float db1v = ws[OFF_DB1s + tid];
  h0s[0][tid] = 0.f; h0s[1][tid] = 0.f;
  h1s[0][tid] = 0.f; h1s[1][tid] = 0.f;
  __syncthreads();
  for (int t = 0; t < TSTEPS; ++t) {
    {
      const int r = tid / 132, i = tid - r * 132;
      xb[r][i] = (i < IND) ? X[((size_t)t * BATCH + r0 + r) * IND + i] : 0.f;
      if (tid < 8) {
        const int i2 = tid + 124;
        xb[1][i2] = (i2 < IND) ? X[((size_t)t * BATCH + r0 + 1) * IND + i2] : 0.f;
      }
    }
    __syncthreads();
    const float2 a = layer_in(ew0, eh0, xb[0], xb[1], h0s[0], h0s[1], eb0v, tid);
    const float n0a = ftanh(a.x), n0b = ftanh(a.y);
    __syncthreads();
    h0s[0][tid] = n0a; h0s[1][tid] = n0b;
    __syncthreads();
    const float2 b = layer_hh(ew1, eh1, h0s[0], h0s[1], h1s[0], h1s[1], eb1v, tid);
    const float n1a = ftanh(b.x), n1b = ftanh(b.y);
    __syncthreads();
    h1s[0][tid] = n1a; h1s[1][tid] = n1b;
    __syncthreads();
  }
  for (int t = 0; t < TSTEPS; ++t) {
    const float* xbase = (t == 0) ? (X + (size_t)TSTEPS * BATCH * IND)
                                  : (Y + (size_t)(t - 1) * BATCH * IND);
    {
      const int r = tid / 132, i = tid - r * 132;
      xb[r][i] = (i < IND) ? xbase[(size_t)(r0 + r) * IND + i] : 0.f;
      if (tid < 8) {
        const int i2 = tid + 124;
        xb[1][i2] = (i2 < IND) ? xbase[(size_t)(r0 + 1) * IND + i2] : 0.f;
      }
    }
    __syncthreads();
    const float2 a = layer_in(dw0, dh0, xb[0], xb[1], h0s[0], h0s[1], db0v, tid);
    const float n0a = ftanh(a.x), n0b = ftanh(a.y);
    __syncthreads();
    h0s[0][tid] = n0a; h0s[1][tid] = n0b;
    __syncthreads();
    const float2 b = layer_hh(dw1, dh1, h0s[0], h0s[1], h1s[0], h1s[1], db1v, tid);
    const float n1a = ftanh(b.x), n1b = ftanh(b.y);
    __syncthreads();
    h1s[0][tid] = n1a; h1s[1][tid] = n1b;
    __syncthreads();
    if (tid < OUTD) {
      float c0 = linb[tid], c1 = linb[tid];
#pragma unroll 4
      for (int k4 = 0; k4 < 64; ++k4) {
        const float4 w = lw[k4 * OUTD + tid];
        c0 = dot4(*(const float4*)&h1s[0][k4 * 4], w, c0);
        c1 = dot4(*(const float4*)&h1s[1][k4 * 4], w, c1);
      }
      lo[0][tid] = c0;
      lo[1][tid] = c1;
    }
    __syncthreads();
    const int wid = tid >> 6, lane = tid & 63;
    if (wid < 2) {
      float m = -3.0e38f;
      for (int o = lane; o < OUTD; o += 64) m = fmaxf(m, lo[wid][o]);
#pragma unroll
      for (int off = 32; off > 0; off >>= 1) m = fmaxf(m, __shfl_xor(m, off, 64));
      float s = 0.f;
      for (int o = lane; o < OUTD; o += 64) s += __expf(lo[wid][o] - m);
#pragma unroll
      for (int off = 32; off > 0; off >>= 1) s += __shfl_xor(s, off, 64);
      const float lse = m + __logf(s);
      float* op = out + ((size_t)t * BATCH + r0 + wid) * OUTD;
      for (int o = lane; o < OUTD; o += 64) op[o] = lo[wid][o] - lse;
    }
    __syncthreads();
  }
}

// ================================ launcher =================================
extern "C" void kernel_launch(void* const* d_in, const int* in_sizes, int n_in,
                              void* d_out, int out_size, void* d_ws, size_t ws_size,
                              hipStream_t stream) {
  const float* X      = (const float*)d_in[0];
  const float* Y      = (const float*)d_in[1];
  const float* eW0    = (const float*)d_in[2];
  const float* eH0    = (const float*)d_in[3];
  const float* eb_ih0 = (const float*)d_in[4];
  const float* eb_hh0 = (const float*)d_in[5];
  const float* eW1    = (const float*)d_in[6];
  const float* eH1    = (const float*)d_in[7];
  const float* eb_ih1 = (const float*)d_in[8];
  const float* eb_hh1 = (const float*)d_in[9];
  const float* dW0    = (const float*)d_in[10];
  const float* dH0    = (const float*)d_in[11];
  const float* db_ih0 = (const float*)d_in[12];
  const float* db_hh0 = (const float*)d_in[13];
  const float* dW1    = (const float*)d_in[14];
  const float* dH1    = (const float*)d_in[15];
  const float* db_ih1 = (const float*)d_in[16];
  const float* db_hh1 = (const float*)d_in[17];
  const float* linW   = (const float*)d_in[18];
  const float* linb   = (const float*)d_in[19];
  float* out = (float*)d_out;

  if (ws_size >= TOTAL_WS) {
    float* buf0 = (float*)d_ws;
    float* buf1 = (float*)((char*)d_ws + SB);
    unsigned short* pk = (unsigned short*)((char*)d_ws + PKB);
    float* bfin = (float*)((char*)d_ws + BFB);
    float* be0 = bfin, *be1 = bfin + 256, *bd0 = bfin + 512, *bd1 = bfin + 768;
    float* blin = bfin + 1024;
    float* fin0 = bfin + FIN0;
    float* fin1 = bfin + FIN1;
    const float* X1023 = X + (size_t)TSTEPS * BATCH * IND;

    prep_pack<<<2005, 256, 0, stream>>>(eW0, eH0, eb_ih0, eb_hh0, eW1, eH1, eb_ih1,
                                        eb_hh1, dW0, dH0, db_ih0, db_hh0, dW1, dH1,
                                        db_ih1, db_hh1, linW, linb, pk, bfin);
    // encoder layer 0
    gemm_proj<<<dim3(MTOT / 64, 4), 256, 0, stream>>>(
        X, nullptr, nullptr, 0, IND, 5, pk + EW0, pk + EW0 + 40960, be0, buf0);
    scan_kernel<<<16, 512, 0, stream>>>(buf0, pk + UE0, nullptr, fin0);
    // encoder layer 1
    gemm_proj<<<dim3(MTOT / 64, 4), 256, 0, stream>>>(
        buf0, nullptr, nullptr, 0, 256, 8, pk + EW1, pk + EW1 + 65536, be1, buf1);
    scan_kernel<<<16, 512, 0, stream>>>(buf1, pk + UE1, nullptr, fin1);
    // decoder layer 0 (teacher forcing inputs)
    gemm_proj<<<dim3(MTOT / 64, 4), 256, 0, stream>>>(
        nullptr, X1023, Y, 1, IND, 5, pk + DW0, pk + DW0 + 40960, bd0, buf0);
    scan_kernel<<<16, 512, 0, stream>>>(buf0, pk + UD0, fin0, nullptr);
    // decoder layer 1
    gemm_proj<<<dim3(MTOT / 64, 4), 256, 0, stream>>>(
        buf0, nullptr, nullptr, 0, 256, 8, pk + DW1, pk + DW1 + 65536, bd1, buf1);
    scan_kernel<<<16, 512, 0, stream>>>(buf1, pk + UD1, fin1, nullptr);
    // linear head + log_softmax
    head_kernel<<<MTOT / 64, 256, 0, stream>>>(buf1, pk + LINP, pk + LINP + 36864,
                                               blin, out);
  } else {
    float* ws = (float*)d_ws;
    prep_slow<<<(WS_TOTAL_SLOW + 255) / 256, 256, 0, stream>>>(
        eW0, eH0, eb_ih0, eb_hh0, eW1, eH1, eb_ih1, eb_hh1,
        dW0, dH0, db_ih0, db_hh0, dW1, dH1, db_ih1, db_hh1, linW, ws);
    rnn_slow<<<128, 256, 0, stream>>>(X, Y, ws, linb, out);
  }
}